// Round 6
// baseline (741.305 us; speedup 1.0000x reference)
//
#include <hip/hip_runtime.h>

// T=512, B=512, K=8, V=5, H=30, NL=4, NLAB=3
#define TT 512
#define BB 512
#define KK 8
#define HH 30
#define GG 120
#define NLAYER 4
#define NS 16     // samples per pipeline block
#define SBN 32    // sample blocks (SBN*NS = BB)

typedef _Float16 f16x8 __attribute__((ext_vector_type(8)));
typedef _Float16 f16x2 __attribute__((ext_vector_type(2)));
typedef float    f32x4 __attribute__((ext_vector_type(4)));

// d_ws layout in halfs: [0, SEQSZ) = seq, later overwritten in-place by h3
// (wave-3 writes trail wave-0 seq prefetch by >=12 steps); frags after.
#define SEQSZ_H   (SBN*TT*NS*32)          // 8,388,608 halfs = 16 MB
#define FRAG_OFF_H SEQSZ_H                // 4*8*64*3*8 = 49152 halfs

__device__ __forceinline__ float rcp_f(float x){ return __builtin_amdgcn_rcpf(x); }
__device__ __forceinline__ float sigf(float x){ return rcp_f(1.f + __expf(-x)); }
__device__ __forceinline__ float tanhf_(float x){ return fmaf(2.f, rcp_f(1.f + __expf(-2.f*x)), -1.f); }
__device__ __forceinline__ int pack2h(float a, float b){
    return __builtin_bit_cast(int, __builtin_amdgcn_cvt_pkrtz(a, b));
}
__device__ __forceinline__ float rdlane_f(float v, int l){
    return __int_as_float(__builtin_amdgcn_readlane(__float_as_int(v), l));
}
__device__ __forceinline__ float fdot2_sv(int bs, int wreg, float acc){
    float d;
    asm("v_dot2_f32_f16 %0, %1, %2, %3" : "=v"(d) : "s"(bs), "v"(wreg), "v"(acc));
    return d;
}

// ---------------- kernel 1: embed-pool -> seq, and A-fragment prep ----------
// A matrix per layer (128 rows x 64 cols), gate rows padded to 32:
//   rows: i=0..31, f=32..63, g=64..95, o=96..127 (unit j at gate*32+j, j<30)
//   cols: 0-29 Wih, 30-31 zero, 32-61 Whh, 62 bias(bih+bhh), 63 zero
// Frags: A[m=lane&15][k=quad*8+j]; hi/lo split for chunk1 (recurrent).
__global__ __launch_bounds__(256) void prep_kernel(
    const int* __restrict__ xin, const float* __restrict__ wxin,
    const float* __restrict__ embed,
    const float* __restrict__ Wih, const float* __restrict__ Whh,
    const float* __restrict__ bih, const float* __restrict__ bhh,
    _Float16* __restrict__ wsh)
{
    const int tid = threadIdx.x;
    if (blockIdx.x == SBN*32) {            // ---- frag-prep block ----
        const int wv = tid >> 6, lane = tid & 63;
        const int mA = lane & 15, q = lane >> 4;
        const float* WihL = Wih + wv*GG*HH;
        const float* WhhL = Whh + wv*GG*HH;
        _Float16* fr = wsh + FRAG_OFF_H;
        #pragma unroll
        for (int u = 0; u < 8; ++u) {
            const int R = u*16 + mA, gate = R >> 5, j = R & 31;
            const bool valid = (j < HH);
            const int src = gate*HH + j;
            f16x8 a0h, a1h, a1l;
            #pragma unroll
            for (int jj = 0; jj < 8; ++jj) {
                const int k = q*8 + jj;
                float v0 = (valid && k < HH) ? WihL[src*HH + k] : 0.f;
                a0h[jj] = (_Float16)v0;
                float v1 = 0.f;
                if (valid) {
                    if (k < HH)       v1 = WhhL[src*HH + k];
                    else if (k == HH) v1 = bih[wv*GG + src] + bhh[wv*GG + src];
                }
                _Float16 h = (_Float16)v1;
                a1h[jj] = h;
                a1l[jj] = (_Float16)(v1 - (float)h);
            }
            const int idx = ((wv*8 + u)*64 + lane)*3;
            *(f16x8*)(fr + (size_t)(idx+0)*8) = a0h;
            *(f16x8*)(fr + (size_t)(idx+1)*8) = a1h;
            *(f16x8*)(fr + (size_t)(idx+2)*8) = a1l;
        }
        return;
    }
    // ---- embed-pool blocks: 32 sb x 32 tchunks ----
    __shared__ float re_s[5*HH];
    if (tid < 5*HH) re_s[tid] = fmaxf(embed[tid], 0.f);
    __syncthreads();
    const int sb = blockIdx.x >> 5, tc = blockIdx.x & 31;
    const int tt = tid >> 4, n = tid & 15;
    const int t = tc*16 + tt;
    const int b = sb*NS + n;
    const int4*   xp = (const int4*)  (xin  + ((size_t)t*BB + b)*KK);
    const float4* wp = (const float4*)(wxin + ((size_t)t*BB + b)*KK);
    const int4  xa = xp[0], xb = xp[1];
    const float4 wa = wp[0], wb = wp[1];
    float acc[HH];
    #pragma unroll
    for (int j = 0; j < HH; ++j) acc[j] = 0.f;
    const int   xv[8] = {xa.x, xa.y, xa.z, xa.w, xb.x, xb.y, xb.z, xb.w};
    const float wv8[8] = {wa.x, wa.y, wa.z, wa.w, wb.x, wb.y, wb.z, wb.w};
    #pragma unroll
    for (int k = 0; k < 8; ++k) {
        const float* row = re_s + xv[k]*HH;
        const float w = wv8[k];
        #pragma unroll
        for (int j = 0; j < HH; ++j) acc[j] = fmaf(row[j], w, acc[j]);
    }
    int s[16];
    #pragma unroll
    for (int jp = 0; jp < 15; ++jp)
        s[jp] = pack2h(acc[2*jp]*0.125f, acc[2*jp+1]*0.125f);
    s[15] = 0;                               // slots 30,31 = 0
    int4* dst = (int4*)(wsh + (((size_t)sb*TT + t)*NS + n)*32);
    dst[0] = make_int4(s[0],  s[1],  s[2],  s[3]);
    dst[1] = make_int4(s[4],  s[5],  s[6],  s[7]);
    dst[2] = make_int4(s[8],  s[9],  s[10], s[11]);
    dst[3] = make_int4(s[12], s[13], s[14], s[15]);
}

// ---------------- kernel 2: 4-layer LSTM pipeline, 16 samples/block --------
__global__ __launch_bounds__(256, 1) void rnn_pipe(_Float16* __restrict__ wsh)
{
    __shared__ _Float16 Hhi[NLAYER][4][NS][32];   // 4-deep h ring, hi
    __shared__ _Float16 Hlo[NLAYER][4][NS][32];   // lo residuals
    __shared__ int prog_s[NLAYER], cons_s[NLAYER];
    const int tid = threadIdx.x, wv = tid >> 6, lane = tid & 63;
    const int n = lane & 15, q = lane >> 4;
    const int sb = blockIdx.x;

    for (int i = tid; i < NLAYER*4*NS*32/2; i += 256) {
        ((int*)Hhi)[i] = 0; ((int*)Hlo)[i] = 0;
    }
    if (tid < NLAYER) { prog_s[tid] = 0; cons_s[tid] = 0; }
    __syncthreads();
    if (tid < NLAYER*4*NS) {                 // bias slot: Hhi[l][rg][nn][30]=1
        const int l = tid >> 6, rg = (tid >> 4) & 3, nn = tid & 15;
        Hhi[l][rg][nn][30] = (_Float16)1.0f;
    }
    f16x8 a0h[8], a1h[8], a1l[8];
    {
        const _Float16* fr = wsh + FRAG_OFF_H;
        #pragma unroll
        for (int u = 0; u < 8; ++u) {
            const int idx = ((wv*8 + u)*64 + lane)*3;
            a0h[u] = *(const f16x8*)(fr + (size_t)(idx+0)*8);
            a1h[u] = *(const f16x8*)(fr + (size_t)(idx+1)*8);
            a1l[u] = *(const f16x8*)(fr + (size_t)(idx+2)*8);
        }
    }
    const _Float16* seqb = wsh + (size_t)sb*TT*NS*32 + n*32 + q*8;  // frag addr
    _Float16*       h3b  = wsh + (size_t)sb*TT*NS*32 + n*32;        // overlay
    __syncthreads();

    float c0[4] = {0,0,0,0}, c1[4] = {0,0,0,0};
    f16x8 sA[2], sB[2], sC[2];
    if (wv == 0) {
        #pragma unroll
        for (int i = 0; i < 2; ++i) {
            sA[i] = *(const f16x8*)(seqb + (size_t)(0+i)*(NS*32));
            sB[i] = *(const f16x8*)(seqb + (size_t)(2+i)*(NS*32));
            sC[i] = *(const f16x8*)(seqb + (size_t)(4+i)*(NS*32));
        }
    }
    volatile int* vprog = prog_s;
    volatile int* vcons = cons_s;

    for (int t0 = 0; t0 < TT; t0 += 2) {
        if (wv > 0)          while (vprog[wv-1] < t0+2) __builtin_amdgcn_s_sleep(1);
        if (wv < NLAYER-1)   while (vcons[wv+1] < t0-2) __builtin_amdgcn_s_sleep(1);
        asm volatile("" ::: "memory");
        #pragma unroll
        for (int ttp = 0; ttp < 2; ++ttp) {
            const int t = t0 + ttp;
            f16x8 b0;
            if (wv == 0) b0 = sA[ttp];
            else         b0 = *(const f16x8*)(&Hhi[wv-1][t&3][n][q*8]);
            const f16x8 b1h = *(const f16x8*)(&Hhi[wv][(t+3)&3][n][q*8]);
            const f16x8 b1l = *(const f16x8*)(&Hlo[wv][(t+3)&3][n][q*8]);
            f32x4 acc[8];
            #pragma unroll
            for (int u = 0; u < 8; ++u) {
                f32x4 d = {0.f, 0.f, 0.f, 0.f};
                d = __builtin_amdgcn_mfma_f32_16x16x32_f16(a0h[u], b0,  d, 0, 0, 0);
                d = __builtin_amdgcn_mfma_f32_16x16x32_f16(a1h[u], b1h, d, 0, 0, 0);
                d = __builtin_amdgcn_mfma_f32_16x16x32_f16(a1h[u], b1l, d, 0, 0, 0);
                d = __builtin_amdgcn_mfma_f32_16x16x32_f16(a1l[u], b1h, d, 0, 0, 0);
                acc[u] = d;
            }
            // D: sample n = lane&15; gate-row = 16u + 4q + r. All 4 gates of a
            // unit are in-lane thanks to 32-aligned gate padding.
            float hv0[4], hv1[4];
            #pragma unroll
            for (int r = 0; r < 4; ++r) {
                {   const float si = sigf(acc[0][r]), sf = sigf(acc[2][r]);
                    const float tg = tanhf_(acc[4][r]), so = sigf(acc[6][r]);
                    c0[r] = fmaf(sf, c0[r], si*tg);
                    hv0[r] = so * tanhf_(c0[r]); }
                {   const float si = sigf(acc[1][r]), sf = sigf(acc[3][r]);
                    const float tg = tanhf_(acc[5][r]), so = sigf(acc[7][r]);
                    c1[r] = fmaf(sf, c1[r], si*tg);
                    hv1[r] = so * tanhf_(c1[r]); }
            }
            const int h0a = pack2h(hv0[0], hv0[1]), h0b = pack2h(hv0[2], hv0[3]);
            const int h1a = pack2h(hv1[0], hv1[1]), h1b = pack2h(hv1[2], hv1[3]);
            const f16x2 q0a = __builtin_bit_cast(f16x2, h0a), q0b = __builtin_bit_cast(f16x2, h0b);
            const f16x2 q1a = __builtin_bit_cast(f16x2, h1a), q1b = __builtin_bit_cast(f16x2, h1b);
            const int l0a = pack2h(hv0[0]-(float)q0a[0], hv0[1]-(float)q0a[1]);
            const int l0b = pack2h(hv0[2]-(float)q0b[0], hv0[3]-(float)q0b[1]);
            const int l1a = pack2h(hv1[0]-(float)q1a[0], hv1[1]-(float)q1a[1]);
            const int l1b = pack2h(hv1[2]-(float)q1b[0], hv1[3]-(float)q1b[1]);
            *(int2*)&Hhi[wv][t&3][n][4*q] = make_int2(h0a, h0b);
            *(int2*)&Hlo[wv][t&3][n][4*q] = make_int2(l0a, l0b);
            if (q < 3) {
                *(int2*)&Hhi[wv][t&3][n][16+4*q] = make_int2(h1a, h1b);
                *(int2*)&Hlo[wv][t&3][n][16+4*q] = make_int2(l1a, l1b);
            } else {     // units 30,31 are pad; keep bias slot intact
                *(int*)&Hhi[wv][t&3][n][28] = h1a;
                *(int*)&Hlo[wv][t&3][n][28] = l1a;
            }
            if (wv == NLAYER-1) {
                _Float16* hr = h3b + (size_t)t*(NS*32);
                *(int2*)(hr + 4*q) = make_int2(h0a, h0b);
                if (q < 3) *(int2*)(hr + 16 + 4*q) = make_int2(h1a, h1b);
                else       *(int*) (hr + 28) = h1a;
            }
        }
        if (wv == 0) {                       // rotate seq prefetch (6 ahead)
            sA[0] = sB[0]; sA[1] = sB[1]; sB[0] = sC[0]; sB[1] = sC[1];
            const int tl0 = (t0+6 < TT) ? t0+6 : TT-1;
            const int tl1 = (t0+7 < TT) ? t0+7 : TT-1;
            sC[0] = *(const f16x8*)(seqb + (size_t)tl0*(NS*32));
            sC[1] = *(const f16x8*)(seqb + (size_t)tl1*(NS*32));
        }
        asm volatile("s_waitcnt lgkmcnt(0)" ::: "memory");  // drain DS, not vmcnt
        if (lane == 0) {
            if (wv < NLAYER-1) vprog[wv] = t0 + 2;
            if (wv > 0)        vcons[wv] = t0 + 2;
        }
    }
}

// ---------------- kernel 3: attention + softmax + FC per sample ------------
__global__ __launch_bounds__(64) void attn_kernel(
    const _Float16* __restrict__ wsh,
    const float* __restrict__ W1, const float* __restrict__ b1,
    const float* __restrict__ W2, const float* __restrict__ b2,
    const float* __restrict__ fcW, const float* __restrict__ fcb,
    float* __restrict__ out)
{
    const int bs = blockIdx.x, sb = bs >> 4, n = bs & 15;
    const int lane = threadIdx.x;
    const _Float16* hb = wsh + ((size_t)sb*TT*NS + n)*32;
    int w1p[15];
    #pragma unroll
    for (int k = 0; k < 15; ++k)
        w1p[k] = pack2h(W1[(2*k)*64 + lane], W1[(2*k+1)*64 + lane]);
    const float b1v = b1[lane], w2v = W2[lane], b2v = b2[0];
    float en[8];
    #pragma unroll
    for (int pass = 0; pass < 8; ++pass) {
        const int t = pass*64 + lane;
        const int* hp = (const int*)(hb + (size_t)t*(NS*32));
        int h2[15];
        #pragma unroll
        for (int k = 0; k < 15; ++k) h2[k] = hp[k];
        float e = b2v;
        for (int u = 0; u < 64; ++u) {
            float acc = rdlane_f(b1v, u);
            #pragma unroll
            for (int k = 0; k < 15; ++k)
                acc = fdot2_sv(__builtin_amdgcn_readlane(w1p[k], u), h2[k], acc);
            e = fmaf(fmaxf(acc, 0.f), rdlane_f(w2v, u), e);
        }
        en[pass] = e;
    }
    float mx = en[0];
    #pragma unroll
    for (int p = 1; p < 8; ++p) mx = fmaxf(mx, en[p]);
    #pragma unroll
    for (int m = 1; m < 64; m <<= 1) mx = fmaxf(mx, __shfl_xor(mx, m, 64));
    float ssum = 0.f;
    #pragma unroll
    for (int p = 0; p < 8; ++p) { en[p] = __expf(en[p] - mx); ssum += en[p]; }
    #pragma unroll
    for (int m = 1; m < 64; m <<= 1) ssum += __shfl_xor(ssum, m, 64);
    const float invS = rcp_f(ssum);
    float px[15], py[15];
    #pragma unroll
    for (int k = 0; k < 15; ++k) { px[k] = 0.f; py[k] = 0.f; }
    #pragma unroll
    for (int pass = 0; pass < 8; ++pass) {
        const int t = pass*64 + lane;
        const int* hp = (const int*)(hb + (size_t)t*(NS*32));
        const float w = en[pass] * invS;
        #pragma unroll
        for (int k = 0; k < 15; ++k) {
            const f16x2 hh = __builtin_bit_cast(f16x2, hp[k]);
            px[k] = fmaf(w, (float)hh[0], px[k]);
            py[k] = fmaf(w, (float)hh[1], py[k]);
        }
    }
    #pragma unroll
    for (int m = 1; m < 64; m <<= 1) {
        #pragma unroll
        for (int k = 0; k < 15; ++k) {
            px[k] += __shfl_xor(px[k], m, 64);
            py[k] += __shfl_xor(py[k], m, 64);
        }
    }
    if (lane == 0) {
        float lg[3];
        #pragma unroll
        for (int i = 0; i < 3; ++i) {
            float a = fcb[i];
            #pragma unroll
            for (int k = 0; k < 15; ++k) {
                a = fmaf(px[k], fcW[(2*k)*3 + i], a);
                a = fmaf(py[k], fcW[(2*k+1)*3 + i], a);
            }
            lg[i] = a;
        }
        const float m3 = fmaxf(lg[0], fmaxf(lg[1], lg[2]));
        const float e0 = __expf(lg[0]-m3), e1 = __expf(lg[1]-m3), e2 = __expf(lg[2]-m3);
        const float inv = rcp_f(e0 + e1 + e2);
        out[bs*3+0] = e0*inv; out[bs*3+1] = e1*inv; out[bs*3+2] = e2*inv;
    }
}

extern "C" void kernel_launch(void* const* d_in, const int* in_sizes, int n_in,
                              void* d_out, int out_size, void* d_ws, size_t ws_size,
                              hipStream_t stream)
{
    (void)in_sizes; (void)n_in; (void)ws_size; (void)out_size;
    _Float16* wsh = (_Float16*)d_ws;
    prep_kernel<<<SBN*32 + 1, 256, 0, stream>>>(
        (const int*)  d_in[0], (const float*)d_in[1], (const float*)d_in[2],
        (const float*)d_in[3], (const float*)d_in[4], (const float*)d_in[5],
        (const float*)d_in[6], wsh);
    rnn_pipe<<<SBN, 256, 0, stream>>>(wsh);
    attn_kernel<<<BB, 64, 0, stream>>>(
        wsh, (const float*)d_in[7], (const float*)d_in[8], (const float*)d_in[9],
        (const float*)d_in[10], (const float*)d_in[11], (const float*)d_in[12],
        (float*)d_out);
}

// Round 7
// 708.798 us; speedup vs baseline: 1.0459x; 1.0459x over previous
//
#include <hip/hip_runtime.h>

// T=512, B=512, K=8, V=5, H=30, NL=4, NLAB=3
#define TT 512
#define BB 512
#define KK 8
#define HH 30
#define GG 120
#define NLAYER 4
#define NS 16     // samples per pipeline
#define SBN 32    // pipelines (SBN*NS = BB)

typedef _Float16 f16x8 __attribute__((ext_vector_type(8)));
typedef _Float16 f16x2 __attribute__((ext_vector_type(2)));
typedef float    f32x4 __attribute__((ext_vector_type(4)));

// d_ws (halfs): [0, SEQSZ) seq, overwritten in place by layer-3 h (writes
// trail wave-0 reads); A-fragments after.
#define SEQSZ_H    (SBN*TT*NS*32)       // 16 MB
#define FRAG_OFF_H SEQSZ_H

__device__ __forceinline__ float rcp_f(float x){ return __builtin_amdgcn_rcpf(x); }
__device__ __forceinline__ int pack2h(float a, float b){
    return __builtin_bit_cast(int, __builtin_amdgcn_cvt_pkrtz(a, b));
}
__device__ __forceinline__ float rdlane_f(float v, int l){
    return __int_as_float(__builtin_amdgcn_readlane(__float_as_int(v), l));
}
__device__ __forceinline__ float fdot2_sv(int bs, int wreg, float acc){
    float d;
    asm("v_dot2_f32_f16 %0, %1, %2, %3" : "=v"(d) : "s"(bs), "v"(wreg), "v"(acc));
    return d;
}

// ---------------- kernel 1: embed-pool -> seq + A-fragment prep -------------
// A row R (tile u, row m): gate = u>>1 (i,f,g,o), unit = 2m + (u&1).
// cols: k<30 = Wih (a0h) / Whh (a1h,a1l); k==30 = bias (a1h hi, a1l lo); 31 = 0.
// This mapping makes MFMA D-layout identical to the B-fragment layout:
// lane(n,q) produces h for units 8q..8q+7 of sample n == its own next B-frag.
__global__ __launch_bounds__(256) void prep_kernel(
    const int* __restrict__ xin, const float* __restrict__ wxin,
    const float* __restrict__ embed,
    const float* __restrict__ Wih, const float* __restrict__ Whh,
    const float* __restrict__ bih, const float* __restrict__ bhh,
    _Float16* __restrict__ wsh)
{
    const int tid = threadIdx.x;
    if (blockIdx.x == SBN*32) {            // ---- frag-prep block ----
        const int wv = tid >> 6, lane = tid & 63;
        const int mA = lane & 15, qq = lane >> 4;
        const float* WihL = Wih + wv*GG*HH;
        const float* WhhL = Whh + wv*GG*HH;
        _Float16* fr = wsh + FRAG_OFF_H;
        #pragma unroll
        for (int u = 0; u < 8; ++u) {
            const int gate = u >> 1;
            const int unit = 2*mA + (u & 1);
            const bool valid = (unit < HH);
            const int src = gate*HH + unit;          // PyTorch gate-row
            f16x8 a0hv, a1hv, a1lv;
            #pragma unroll
            for (int jj = 0; jj < 8; ++jj) {
                const int k = qq*8 + jj;
                float v0 = (valid && k < HH) ? WihL[src*HH + k] : 0.f;
                a0hv[jj] = (_Float16)v0;
                float v1 = 0.f;
                if (valid) {
                    if (k < HH)       v1 = WhhL[src*HH + k];
                    else if (k == HH) v1 = bih[wv*GG + src] + bhh[wv*GG + src];
                }
                _Float16 h = (_Float16)v1;
                a1hv[jj] = h;
                a1lv[jj] = (_Float16)(v1 - (float)h);
            }
            const int idx = ((wv*8 + u)*64 + lane)*3;
            *(f16x8*)(fr + (size_t)(idx+0)*8) = a0hv;
            *(f16x8*)(fr + (size_t)(idx+1)*8) = a1hv;
            *(f16x8*)(fr + (size_t)(idx+2)*8) = a1lv;
        }
        return;
    }
    // ---- embed-pool blocks: 32 sb x 32 tchunks ----
    __shared__ float re_s[5*HH];
    if (tid < 5*HH) re_s[tid] = fmaxf(embed[tid], 0.f);
    __syncthreads();
    const int sb = blockIdx.x >> 5, tc = blockIdx.x & 31;
    const int tt = tid >> 4, n = tid & 15;
    const int t = tc*16 + tt;
    const int b = sb*NS + n;
    const int4*   xp = (const int4*)  (xin  + ((size_t)t*BB + b)*KK);
    const float4* wp = (const float4*)(wxin + ((size_t)t*BB + b)*KK);
    const int4  xa = xp[0], xb = xp[1];
    const float4 wa = wp[0], wb = wp[1];
    float acc[HH];
    #pragma unroll
    for (int j = 0; j < HH; ++j) acc[j] = 0.f;
    const int   xv[8]  = {xa.x, xa.y, xa.z, xa.w, xb.x, xb.y, xb.z, xb.w};
    const float wv8[8] = {wa.x, wa.y, wa.z, wa.w, wb.x, wb.y, wb.z, wb.w};
    #pragma unroll
    for (int k = 0; k < 8; ++k) {
        const float* row = re_s + xv[k]*HH;
        const float w = wv8[k];
        #pragma unroll
        for (int j = 0; j < HH; ++j) acc[j] = fmaf(row[j], w, acc[j]);
    }
    int s[16];
    #pragma unroll
    for (int jp = 0; jp < 15; ++jp)
        s[jp] = pack2h(acc[2*jp]*0.125f, acc[2*jp+1]*0.125f);
    s[15] = 0;                                       // k=30,31 zero
    int4* dst = (int4*)(wsh + (((size_t)sb*TT + t)*NS + n)*32);
    dst[0] = make_int4(s[0],  s[1],  s[2],  s[3]);
    dst[1] = make_int4(s[4],  s[5],  s[6],  s[7]);
    dst[2] = make_int4(s[8],  s[9],  s[10], s[11]);
    dst[3] = make_int4(s[12], s[13], s[14], s[15]);
}

// ---------------- kernel 2: 4-layer LSTM pipeline, register recurrence ------
__global__ __launch_bounds__(256, 1) void rnn_pipe(_Float16* __restrict__ wsh)
{
    __shared__ alignas(16) _Float16 ring[3][8][NS][32];  // inter-layer h (hi)
    __shared__ int prog_s[4], cons_s[4];
    const int tid = threadIdx.x, wv = tid >> 6, lane = tid & 63;
    const int n = lane & 15, q = lane >> 4;
    const int sb = blockIdx.x;
    if (tid < 4) { prog_s[tid] = 0; cons_s[tid] = 0; }

    f16x8 a0h[8], a1h[8], a1l[8];
    {
        const _Float16* fr = wsh + FRAG_OFF_H;
        #pragma unroll
        for (int u = 0; u < 8; ++u) {
            const int idx = ((wv*8 + u)*64 + lane)*3;
            a0h[u] = *(const f16x8*)(fr + (size_t)(idx+0)*8);
            a1h[u] = *(const f16x8*)(fr + (size_t)(idx+1)*8);
            a1l[u] = *(const f16x8*)(fr + (size_t)(idx+2)*8);
        }
    }
    const _Float16* seqb = wsh + (size_t)sb*TT*NS*32 + n*32 + q*8;
    __syncthreads();

    // shared-rcp LSTM unit: c' = sig(F)c + sig(I)tanh(G); h = sig(O)tanh(c')
    auto lstm_unit = [&](float I, float F, float G, float O, float& c) -> float {
        const float P  = __expf(-I);
        const float E  = __expf(fminf(2.f*G, 60.f));
        const float Fs = rcp_f(1.f + __expf(-F));
        const float pig = (E - 1.f) * rcp_f((1.f + P)*(1.f + E));
        c = fmaf(Fs, c, pig);
        const float C2 = __expf(fminf(2.f*c, 60.f));
        const float Qo = __expf(-O);
        return (C2 - 1.f) * rcp_f((1.f + Qo)*(1.f + C2));
    };

    const int BIAS1 = 0x00003C00;                 // halfs (1.0, 0.0) at k=30,31
    int4 bh = make_int4(0, 0, 0, (q == 3) ? BIAS1 : 0);   // self h (hi) B-frag
    int4 bl = make_int4(0, 0, 0, 0);                      // self h (lo) B-frag
    float cE[4] = {0,0,0,0}, cO[4] = {0,0,0,0};
    int4 sA0, sA1, sB0, sB1, sC0, sC1;            // wave-0 seq prefetch queue
    if (wv == 0) {
        sA0 = *(const int4*)(seqb + (size_t)0*(NS*32));
        sA1 = *(const int4*)(seqb + (size_t)1*(NS*32));
        sB0 = *(const int4*)(seqb + (size_t)2*(NS*32));
        sB1 = *(const int4*)(seqb + (size_t)3*(NS*32));
        sC0 = *(const int4*)(seqb + (size_t)4*(NS*32));
        sC1 = *(const int4*)(seqb + (size_t)5*(NS*32));
    }
    volatile int* vp = prog_s;
    volatile int* vc = cons_s;

    for (int T0 = 0; T0 < TT; T0 += 2) {
        if (wv > 0) while (vp[wv-1] < T0 + 2) {}         // x window ready
        if (wv < 3) while (vc[wv+1] < T0 - 6) {}         // ring slot free
        f16x8 b0a, b0b;
        if (wv == 0) { b0a = __builtin_bit_cast(f16x8, sA0);
                       b0b = __builtin_bit_cast(f16x8, sA1); }
        else {
            b0a = *(const f16x8*)&ring[wv-1][T0 & 7][n][q*8];
            b0b = *(const f16x8*)&ring[wv-1][(T0+1) & 7][n][q*8];
        }
        #pragma unroll
        for (int ttp = 0; ttp < 2; ++ttp) {
            const int t = T0 + ttp;
            const f16x8 b0   = ttp ? b0b : b0a;
            const f16x8 b1h  = __builtin_bit_cast(f16x8, bh);
            const f16x8 b1lv = __builtin_bit_cast(f16x8, bl);
            f32x4 acc[8];
            #pragma unroll
            for (int u = 0; u < 8; ++u) {
                f32x4 d = {0.f, 0.f, 0.f, 0.f};
                d = __builtin_amdgcn_mfma_f32_16x16x32_f16(a0h[u], b0,   d, 0,0,0);
                d = __builtin_amdgcn_mfma_f32_16x16x32_f16(a1h[u], b1h,  d, 0,0,0);
                d = __builtin_amdgcn_mfma_f32_16x16x32_f16(a1h[u], b1lv, d, 0,0,0);
                d = __builtin_amdgcn_mfma_f32_16x16x32_f16(a1l[u], b1h,  d, 0,0,0);
                acc[u] = d;
            }
            // acc[u][r]: gate u>>1 of unit 8q+2r+(u&1), sample n
            int hi[4], lo[4];
            #pragma unroll
            for (int r = 0; r < 4; ++r) {
                const float hE = lstm_unit(acc[0][r], acc[2][r], acc[4][r], acc[6][r], cE[r]);
                const float hO = lstm_unit(acc[1][r], acc[3][r], acc[5][r], acc[7][r], cO[r]);
                const int hp = pack2h(hE, hO);
                const f16x2 hh = __builtin_bit_cast(f16x2, hp);
                hi[r] = hp;
                lo[r] = pack2h(hE - (float)hh[0], hO - (float)hh[1]);
            }
            bh = make_int4(hi[0], hi[1], hi[2], (q == 3) ? BIAS1 : hi[3]);
            bl = make_int4(lo[0], lo[1], lo[2], (q == 3) ? 0     : lo[3]);
            if (wv < 3)        // contiguous 1024-B wave write: conflict-free
                *(int4*)&ring[wv][t & 7][n][q*8] = make_int4(hi[0], hi[1], hi[2], hi[3]);
            else               // layer-3 h -> global (coalesced dwordx4)
                *(int4*)(wsh + (size_t)sb*TT*NS*32 + (size_t)t*(NS*32) + n*32 + q*8)
                    = make_int4(hi[0], hi[1], hi[2], hi[3]);
        }
        if (wv == 0) {          // rotate prefetch (6 steps ahead)
            sA0 = sB0; sA1 = sB1; sB0 = sC0; sB1 = sC1;
            const int t6 = (T0+6 < TT) ? T0+6 : TT-1;
            const int t7 = (T0+7 < TT) ? T0+7 : TT-1;
            sC0 = *(const int4*)(seqb + (size_t)t6*(NS*32));
            sC1 = *(const int4*)(seqb + (size_t)t7*(NS*32));
        }
        asm volatile("s_waitcnt lgkmcnt(0)" ::: "memory");   // ring writes done
        if (lane == 0) {
            if (wv < 3) vp[wv] = T0 + 2;
            if (wv > 0) vc[wv] = T0 + 2;
        }
    }
}

// ---------------- kernel 3: attention + softmax + FC per sample -------------
__global__ __launch_bounds__(64) void attn_kernel(
    const _Float16* __restrict__ wsh,
    const float* __restrict__ W1, const float* __restrict__ b1,
    const float* __restrict__ W2, const float* __restrict__ b2,
    const float* __restrict__ fcW, const float* __restrict__ fcb,
    float* __restrict__ out)
{
    const int bs = blockIdx.x, sb = bs >> 4, n = bs & 15;
    const int lane = threadIdx.x;
    const _Float16* hb = wsh + ((size_t)sb*TT*NS + n)*32;
    int w1p[15];
    #pragma unroll
    for (int k = 0; k < 15; ++k)
        w1p[k] = pack2h(W1[(2*k)*64 + lane], W1[(2*k+1)*64 + lane]);
    const float b1v = b1[lane], w2v = W2[lane], b2v = b2[0];
    float en[8];
    #pragma unroll
    for (int pass = 0; pass < 8; ++pass) {
        const int t = pass*64 + lane;
        const int* hp = (const int*)(hb + (size_t)t*(NS*32));
        int h2[15];
        #pragma unroll
        for (int k = 0; k < 15; ++k) h2[k] = hp[k];
        float e = b2v;
        for (int u = 0; u < 64; ++u) {
            float a0 = rdlane_f(b1v, u), a1 = 0.f, a2 = 0.f;
            #pragma unroll
            for (int k = 0; k < 5; ++k)
                a0 = fdot2_sv(__builtin_amdgcn_readlane(w1p[k], u), h2[k], a0);
            #pragma unroll
            for (int k = 5; k < 10; ++k)
                a1 = fdot2_sv(__builtin_amdgcn_readlane(w1p[k], u), h2[k], a1);
            #pragma unroll
            for (int k = 10; k < 15; ++k)
                a2 = fdot2_sv(__builtin_amdgcn_readlane(w1p[k], u), h2[k], a2);
            const float su = (a0 + a1) + a2;
            e = fmaf(fmaxf(su, 0.f), rdlane_f(w2v, u), e);
        }
        en[pass] = e;
    }
    float mx = en[0];
    #pragma unroll
    for (int p = 1; p < 8; ++p) mx = fmaxf(mx, en[p]);
    #pragma unroll
    for (int m = 1; m < 64; m <<= 1) mx = fmaxf(mx, __shfl_xor(mx, m, 64));
    float ssum = 0.f;
    #pragma unroll
    for (int p = 0; p < 8; ++p) { en[p] = __expf(en[p] - mx); ssum += en[p]; }
    #pragma unroll
    for (int m = 1; m < 64; m <<= 1) ssum += __shfl_xor(ssum, m, 64);
    const float invS = rcp_f(ssum);
    float px[15], py[15];
    #pragma unroll
    for (int k = 0; k < 15; ++k) { px[k] = 0.f; py[k] = 0.f; }
    #pragma unroll
    for (int pass = 0; pass < 8; ++pass) {
        const int t = pass*64 + lane;
        const int* hp = (const int*)(hb + (size_t)t*(NS*32));
        const float w = en[pass] * invS;
        #pragma unroll
        for (int k = 0; k < 15; ++k) {
            const f16x2 hh = __builtin_bit_cast(f16x2, hp[k]);
            px[k] = fmaf(w, (float)hh[0], px[k]);
            py[k] = fmaf(w, (float)hh[1], py[k]);
        }
    }
    #pragma unroll
    for (int m = 1; m < 64; m <<= 1) {
        #pragma unroll
        for (int k = 0; k < 15; ++k) {
            px[k] += __shfl_xor(px[k], m, 64);
            py[k] += __shfl_xor(py[k], m, 64);
        }
    }
    if (lane == 0) {
        float lg[3];
        #pragma unroll
        for (int i = 0; i < 3; ++i) {
            float a = fcb[i];
            #pragma unroll
            for (int k = 0; k < 15; ++k) {
                a = fmaf(px[k], fcW[(2*k)*3 + i], a);
                a = fmaf(py[k], fcW[(2*k+1)*3 + i], a);
            }
            lg[i] = a;
        }
        const float m3 = fmaxf(lg[0], fmaxf(lg[1], lg[2]));
        const float e0 = __expf(lg[0]-m3), e1 = __expf(lg[1]-m3), e2 = __expf(lg[2]-m3);
        const float inv = rcp_f(e0 + e1 + e2);
        out[bs*3+0] = e0*inv; out[bs*3+1] = e1*inv; out[bs*3+2] = e2*inv;
    }
}

extern "C" void kernel_launch(void* const* d_in, const int* in_sizes, int n_in,
                              void* d_out, int out_size, void* d_ws, size_t ws_size,
                              hipStream_t stream)
{
    (void)in_sizes; (void)n_in; (void)ws_size; (void)out_size;
    _Float16* wsh = (_Float16*)d_ws;
    prep_kernel<<<SBN*32 + 1, 256, 0, stream>>>(
        (const int*)  d_in[0], (const float*)d_in[1], (const float*)d_in[2],
        (const float*)d_in[3], (const float*)d_in[4], (const float*)d_in[5],
        (const float*)d_in[6], wsh);
    rnn_pipe<<<SBN, 256, 0, stream>>>(wsh);
    attn_kernel<<<BB, 64, 0, stream>>>(
        wsh, (const float*)d_in[7], (const float*)d_in[8], (const float*)d_in[9],
        (const float*)d_in[10], (const float*)d_in[11], (const float*)d_in[12],
        (float*)d_out);
}

// Round 8
// 628.180 us; speedup vs baseline: 1.1801x; 1.1283x over previous
//
#include <hip/hip_runtime.h>

// T=512, B=512, K=8, V=5, H=30, NL=4, NLAB=3
#define TT 512
#define BB 512
#define KK 8
#define HH 30
#define GG 120
#define NLAYER 4
#define NS 16     // samples per pipeline block
#define SBN 32    // pipeline blocks (SBN*NS = BB)

typedef _Float16 f16x8 __attribute__((ext_vector_type(8)));
typedef _Float16 f16x2 __attribute__((ext_vector_type(2)));
typedef float    f32x4 __attribute__((ext_vector_type(4)));

// d_ws (halfs): [0, SEQSZ) seq, overwritten in place by layer-3 h (writes
// trail pair-0 reads by >=12 steps; same-CU so L1/L2 coherent); frags after.
#define SEQSZ_H    (SBN*TT*NS*32)       // 16 MB
#define FRAG_OFF_H SEQSZ_H

__device__ __forceinline__ float rcp_f(float x){ return __builtin_amdgcn_rcpf(x); }
__device__ __forceinline__ int pack2h(float a, float b){
    return __builtin_bit_cast(int, __builtin_amdgcn_cvt_pkrtz(a, b));
}
__device__ __forceinline__ int perm_b32(int a, int b, int sel){
    // d.byte[i] = sel.byte[i] in 0..3 -> b.byte, 4..7 -> a.byte
    int d;
    asm("v_perm_b32 %0, %1, %2, %3" : "=v"(d) : "v"(a), "v"(b), "s"(sel));
    return d;
}

// ---------------- kernel 1: embed-pool -> seq + A-fragment prep -------------
// Wave (L,par) owns gate-tiles v=0..3 (gates i,f,g,o), units 2m+par.
// A cols: k<30 Wih (a0h) / Whh (a1h hi, a1l lo); k==30 bias (hi/lo); k==31 0.
// With this remap, MFMA D-layout == B-frag layout: lane(n,q) produces h for
// units 8q+2r+par of sample n — pair interleave rebuilds the full B-frag.
__global__ __launch_bounds__(256) void prep_kernel(
    const int* __restrict__ xin, const float* __restrict__ wxin,
    const float* __restrict__ embed,
    const float* __restrict__ Wih, const float* __restrict__ Whh,
    const float* __restrict__ bih, const float* __restrict__ bhh,
    _Float16* __restrict__ wsh)
{
    const int tid = threadIdx.x;
    if (blockIdx.x == SBN*32) {            // ---- frag-prep block ----
        const int L = tid >> 6, lane = tid & 63;
        const int mA = lane & 15, qq = lane >> 4;
        const float* WihL = Wih + L*GG*HH;
        const float* WhhL = Whh + L*GG*HH;
        _Float16* fr = wsh + FRAG_OFF_H;
        for (int par = 0; par < 2; ++par) {
            const int unit = 2*mA + par;
            const bool valid = (unit < HH);
            #pragma unroll
            for (int v = 0; v < 4; ++v) {            // gate v row
                const int src = v*HH + unit;
                f16x8 a0hv, a1hv, a1lv;
                #pragma unroll
                for (int jj = 0; jj < 8; ++jj) {
                    const int k = qq*8 + jj;
                    float v0 = (valid && k < HH) ? WihL[src*HH + k] : 0.f;
                    a0hv[jj] = (_Float16)v0;
                    float v1 = 0.f;
                    if (valid) {
                        if (k < HH)       v1 = WhhL[src*HH + k];
                        else if (k == HH) v1 = bih[L*GG + src] + bhh[L*GG + src];
                    }
                    _Float16 h = (_Float16)v1;
                    a1hv[jj] = h;
                    a1lv[jj] = (_Float16)(v1 - (float)h);
                }
                const int idx = (((L*2 + par)*4 + v)*64 + lane)*3;
                *(f16x8*)(fr + (size_t)(idx+0)*8) = a0hv;
                *(f16x8*)(fr + (size_t)(idx+1)*8) = a1hv;
                *(f16x8*)(fr + (size_t)(idx+2)*8) = a1lv;
            }
        }
        return;
    }
    // ---- embed-pool blocks: 32 sb x 32 tchunks ----
    __shared__ float re_s[5*HH];
    if (tid < 5*HH) re_s[tid] = fmaxf(embed[tid], 0.f);
    __syncthreads();
    const int sb = blockIdx.x >> 5, tc = blockIdx.x & 31;
    const int tt = tid >> 4, n = tid & 15;
    const int t = tc*16 + tt;
    const int b = sb*NS + n;
    const int4*   xp = (const int4*)  (xin  + ((size_t)t*BB + b)*KK);
    const float4* wp = (const float4*)(wxin + ((size_t)t*BB + b)*KK);
    const int4  xa = xp[0], xb = xp[1];
    const float4 wa = wp[0], wb = wp[1];
    float acc[HH];
    #pragma unroll
    for (int j = 0; j < HH; ++j) acc[j] = 0.f;
    const int   xv[8]  = {xa.x, xa.y, xa.z, xa.w, xb.x, xb.y, xb.z, xb.w};
    const float wv8[8] = {wa.x, wa.y, wa.z, wa.w, wb.x, wb.y, wb.z, wb.w};
    #pragma unroll
    for (int k = 0; k < 8; ++k) {
        const float* row = re_s + xv[k]*HH;
        const float w = wv8[k];
        #pragma unroll
        for (int j = 0; j < HH; ++j) acc[j] = fmaf(row[j], w, acc[j]);
    }
    int s[16];
    #pragma unroll
    for (int jp = 0; jp < 15; ++jp)
        s[jp] = pack2h(acc[2*jp]*0.125f, acc[2*jp+1]*0.125f);
    s[15] = 0;                                       // k=30,31 zero
    int4* dst = (int4*)(wsh + (((size_t)sb*TT + t)*NS + n)*32);
    dst[0] = make_int4(s[0],  s[1],  s[2],  s[3]);
    dst[1] = make_int4(s[4],  s[5],  s[6],  s[7]);
    dst[2] = make_int4(s[8],  s[9],  s[10], s[11]);
    dst[3] = make_int4(s[12], s[13], s[14], s[15]);
}

// ---------------- kernel 2: pipeline + fused attention ----------------------
// 8 waves: pair (2L,2L+1) = layer L row-split. After the recurrence, the same
// block computes energies (MFMA, A=W1^T), softmax, pooling, FC for its 16
// samples — no extra kernels.
__global__ __launch_bounds__(512, 1) void rnn_pipe(
    _Float16* __restrict__ wsh,
    const float* __restrict__ W1, const float* __restrict__ b1,
    const float* __restrict__ W2,
    const float* __restrict__ fcW, const float* __restrict__ fcb,
    float* __restrict__ out)
{
    __shared__ alignas(16) _Float16 ring_s[3][8][NS][32];   // inter-layer h
    __shared__ alignas(16) int2 xch_s[NLAYER][2][2][4][NS]; // [L][par][t&1][q][n]
    __shared__ int pf_s[NLAYER*2];
    __shared__ int vp_s[NLAYER], vc_s[NLAYER];
    __shared__ float energy_s[NS][TT];                       // 32 KB

    const int tid  = threadIdx.x;
    const int wv   = tid >> 6, lane = tid & 63;
    const int L    = wv >> 1, par = wv & 1;
    const int n    = lane & 15, q = lane >> 4;
    const int sb   = blockIdx.x;

    if (tid < NLAYER*2) pf_s[tid] = 0;
    if (tid < NLAYER) { vp_s[tid] = 0; vc_s[tid] = 0; }

    f16x8 a0h[4], a1h[4], a1l[4];
    {
        const _Float16* fr = wsh + FRAG_OFF_H;
        #pragma unroll
        for (int v = 0; v < 4; ++v) {
            const int idx = (((L*2 + par)*4 + v)*64 + lane)*3;
            a0h[v] = *(const f16x8*)(fr + (size_t)(idx+0)*8);
            a1h[v] = *(const f16x8*)(fr + (size_t)(idx+1)*8);
            a1l[v] = *(const f16x8*)(fr + (size_t)(idx+2)*8);
        }
    }
    const _Float16* seqb = wsh + (size_t)sb*TT*NS*32 + n*32 + q*8;
    __syncthreads();

    // shared-rcp LSTM: c' = sig(F)c + sig(I)tanh(G); h = sig(O)tanh(c')
    auto lstm_unit = [&](float I, float F, float G, float O, float& c) -> float {
        const float P  = __expf(-I);
        const float E  = __expf(fminf(2.f*G, 60.f));
        const float Fs = rcp_f(1.f + __expf(-F));
        const float pig = (E - 1.f) * rcp_f((1.f + P)*(1.f + E));
        c = fmaf(Fs, c, pig);
        const float C2 = __expf(fminf(2.f*c, 60.f));
        const float Qo = __expf(-O);
        return (C2 - 1.f) * rcp_f((1.f + Qo)*(1.f + C2));
    };

    const int BIAS1 = 0x00003C00;           // halfs (1.0, 0.0) at k=30,31
    int4 bhw = make_int4(0, 0, 0, (q == 3) ? BIAS1 : 0);  // full-h hi B-frag
    float cc[4] = {0,0,0,0};
    int4 sQ[6];
    if (L == 0) {
        #pragma unroll
        for (int i = 0; i < 6; ++i) sQ[i] = *(const int4*)(seqb + (size_t)i*(NS*32));
    }
    volatile int* pf = pf_s;
    volatile int* vp = vp_s;
    volatile int* vc = vc_s;
    const int selA = 0x01000504, selB = 0x03020706;
    const int L2 = L*2 + par;
    _Float16* h3w = wsh + (size_t)sb*TT*NS*32;

    for (int T0 = 0; T0 < TT; T0 += 2) {
        if (L > 0)            while (vp[L-1] < T0 + 2) {}
        if (par == 0 && L < 3) while (vc[L+1] < T0 - 6) {}
        asm volatile("" ::: "memory");
        f16x8 b0s[2];
        if (L == 0) {
            b0s[0] = __builtin_bit_cast(f16x8, sQ[0]);
            b0s[1] = __builtin_bit_cast(f16x8, sQ[1]);
        } else {
            b0s[0] = *(const f16x8*)&ring_s[L-1][T0 & 7][n][q*8];
            b0s[1] = *(const f16x8*)&ring_s[L-1][(T0+1) & 7][n][q*8];
        }
        #pragma unroll
        for (int tt = 0; tt < 2; ++tt) {
            const int t = T0 + tt;
            const f16x8 bhf = __builtin_bit_cast(f16x8, bhw);
            f32x4 acc[4];
            #pragma unroll
            for (int v = 0; v < 4; ++v) {
                f32x4 d = {0.f,0.f,0.f,0.f};
                d = __builtin_amdgcn_mfma_f32_16x16x32_f16(a0h[v], b0s[tt], d, 0,0,0);
                d = __builtin_amdgcn_mfma_f32_16x16x32_f16(a1h[v], bhf,     d, 0,0,0);
                d = __builtin_amdgcn_mfma_f32_16x16x32_f16(a1l[v], bhf,     d, 0,0,0);
                acc[v] = d;
            }
            float hv4[4];
            #pragma unroll
            for (int r = 0; r < 4; ++r)   // unit 8q+2r+par of sample n
                hv4[r] = lstm_unit(acc[0][r], acc[1][r], acc[2][r], acc[3][r], cc[r]);
            int2 mine;
            mine.x = pack2h(hv4[0], hv4[1]);
            mine.y = pack2h(hv4[2], hv4[3]);
            xch_s[L][par][t & 1][q][n] = mine;
            asm volatile("s_waitcnt lgkmcnt(0)" ::: "memory");
            if (lane == 0) pf[L2] = t + 1;
            while (pf[L2 ^ 1] < t + 1) {}
            asm volatile("" ::: "memory");
            const int2 other = xch_s[L][par ^ 1][t & 1][q][n];
            const int2 ev = par ? other : mine;
            const int2 od = par ? mine  : other;
            bhw.x = perm_b32(ev.x, od.x, selA);
            bhw.y = perm_b32(ev.x, od.x, selB);
            bhw.z = perm_b32(ev.y, od.y, selA);
            bhw.w = (q == 3) ? BIAS1 : perm_b32(ev.y, od.y, selB);
            if (par == 0) {
                if (L < 3) *(int4*)&ring_s[L][t & 7][n][q*8] = bhw;
                else *(int4*)(h3w + (size_t)t*(NS*32) + n*32 + q*8) = bhw;
            }
        }
        if (L == 0) {                  // rotate seq prefetch (6 ahead)
            sQ[0]=sQ[2]; sQ[1]=sQ[3]; sQ[2]=sQ[4]; sQ[3]=sQ[5];
            const int t6 = (T0+6 < TT) ? T0+6 : TT-1;
            const int t7 = (T0+7 < TT) ? T0+7 : TT-1;
            sQ[4] = *(const int4*)(seqb + (size_t)t6*(NS*32));
            sQ[5] = *(const int4*)(seqb + (size_t)t7*(NS*32));
        }
        if (par == 0) {
            asm volatile("s_waitcnt lgkmcnt(0)" ::: "memory");
            if (lane == 0) {
                if (L < 3) vp[L] = T0 + 2;
                if (L > 0) vc[L] = T0 + 2;
            }
        }
    }

    // ================= fused attention (all 8 waves) =================
    asm volatile("s_waitcnt vmcnt(0) lgkmcnt(0)" ::: "memory");
    __syncthreads();

    // energies: e[t] = relu(h_t W1 + b1) . W2   (A = W1^T tiles, B = h rows)
    f16x8 w1f[4];
    #pragma unroll
    for (int v = 0; v < 4; ++v)
        #pragma unroll
        for (int jj = 0; jj < 8; ++jj) {
            const int k = q*8 + jj;
            w1f[v][jj] = (k < HH) ? (_Float16)W1[k*64 + 16*v + n] : (_Float16)0;
        }
    float b1r[4][4], w2r[4][4];
    #pragma unroll
    for (int v = 0; v < 4; ++v)
        #pragma unroll
        for (int r = 0; r < 4; ++r) {
            const int u = 16*v + 4*q + r;
            b1r[v][r] = b1[u];
            w2r[v][r] = W2[u];
        }
    const _Float16* h3b = wsh + (size_t)sb*TT*NS*32;
    #pragma unroll
    for (int ns = 0; ns < 2; ++ns) {
        const int smp = wv*2 + ns;
        for (int t0 = 0; t0 < TT; t0 += 16) {
            const f16x8 hf = *(const f16x8*)(h3b + (size_t)(t0 + n)*(NS*32) + smp*32 + q*8);
            float part = 0.f;
            #pragma unroll
            for (int v = 0; v < 4; ++v) {
                f32x4 d = {0.f,0.f,0.f,0.f};
                d = __builtin_amdgcn_mfma_f32_16x16x32_f16(w1f[v], hf, d, 0,0,0);
                #pragma unroll
                for (int r = 0; r < 4; ++r)
                    part += fmaxf(d[r] + b1r[v][r], 0.f) * w2r[v][r];
            }
            part += __shfl_xor(part, 16, 64);
            part += __shfl_xor(part, 32, 64);
            if (q == 0) energy_s[smp][t0 + n] = part;   // b2 cancels in softmax
        }
    }
    __syncthreads();

    // softmax + pool + FC (2 samples per wave)
    #pragma unroll
    for (int ns = 0; ns < 2; ++ns) {
        const int smp = wv*2 + ns;
        float ev[8];
        float mx = -3.0e38f;
        #pragma unroll
        for (int k2 = 0; k2 < 8; ++k2) {
            ev[k2] = energy_s[smp][k2*64 + lane];
            mx = fmaxf(mx, ev[k2]);
        }
        #pragma unroll
        for (int m = 1; m < 64; m <<= 1) mx = fmaxf(mx, __shfl_xor(mx, m, 64));
        float ss = 0.f;
        #pragma unroll
        for (int k2 = 0; k2 < 8; ++k2) { ev[k2] = __expf(ev[k2] - mx); ss += ev[k2]; }
        #pragma unroll
        for (int m = 1; m < 64; m <<= 1) ss += __shfl_xor(ss, m, 64);
        const float invS = rcp_f(ss);
        float plx[15], ply[15];
        #pragma unroll
        for (int k = 0; k < 15; ++k) { plx[k] = 0.f; ply[k] = 0.f; }
        #pragma unroll
        for (int k2 = 0; k2 < 8; ++k2) {
            const int t = k2*64 + lane;
            const float w = ev[k2] * invS;
            const int* hp = (const int*)(h3b + (size_t)t*(NS*32) + smp*32);
            #pragma unroll
            for (int k = 0; k < 15; ++k) {
                const f16x2 hh = __builtin_bit_cast(f16x2, hp[k]);
                plx[k] = fmaf(w, (float)hh[0], plx[k]);
                ply[k] = fmaf(w, (float)hh[1], ply[k]);
            }
        }
        #pragma unroll
        for (int m = 1; m < 64; m <<= 1) {
            #pragma unroll
            for (int k = 0; k < 15; ++k) {
                plx[k] += __shfl_xor(plx[k], m, 64);
                ply[k] += __shfl_xor(ply[k], m, 64);
            }
        }
        if (lane == 0) {
            float lg[3];
            #pragma unroll
            for (int i = 0; i < 3; ++i) {
                float a = fcb[i];
                #pragma unroll
                for (int k = 0; k < 15; ++k) {
                    a = fmaf(plx[k], fcW[(2*k)*3 + i], a);
                    a = fmaf(ply[k], fcW[(2*k+1)*3 + i], a);
                }
                lg[i] = a;
            }
            const float m3 = fmaxf(lg[0], fmaxf(lg[1], lg[2]));
            const float e0 = __expf(lg[0]-m3), e1 = __expf(lg[1]-m3), e2 = __expf(lg[2]-m3);
            const float inv = rcp_f(e0 + e1 + e2);
            const int bg = (sb*NS + smp)*3;
            out[bg+0] = e0*inv; out[bg+1] = e1*inv; out[bg+2] = e2*inv;
        }
    }
}

extern "C" void kernel_launch(void* const* d_in, const int* in_sizes, int n_in,
                              void* d_out, int out_size, void* d_ws, size_t ws_size,
                              hipStream_t stream)
{
    (void)in_sizes; (void)n_in; (void)ws_size; (void)out_size;
    _Float16* wsh = (_Float16*)d_ws;
    prep_kernel<<<SBN*32 + 1, 256, 0, stream>>>(
        (const int*)  d_in[0], (const float*)d_in[1], (const float*)d_in[2],
        (const float*)d_in[3], (const float*)d_in[4], (const float*)d_in[5],
        (const float*)d_in[6], wsh);
    rnn_pipe<<<SBN, 512, 0, stream>>>(
        wsh, (const float*)d_in[7], (const float*)d_in[8], (const float*)d_in[9],
        (const float*)d_in[11], (const float*)d_in[12], (float*)d_out);
}